// Round 10
// baseline (107.659 us; speedup 1.0000x reference)
//
#include <hip/hip_runtime.h>

// PiecewisePolynomial as a sparse-A dense GEMM (R10).
// out[b,o] = sum_k A[b,k] * W[k,o],  k = i*64 + seg*4 + j  (K=16384)
//   A[b,k]  = (seg(b,i)==s) ? L_j(x_in(b,i)) : 0        (f16, built by pp_prep)
//   W[k,o]  = w[o, i, 3s+j]                              (f16, built by pp_prep)
// pp_gemm: m97-style 2-barrier K-loop, 16x16x32 f16 MFMA, split-K=32,
// 128x128 block tile, VGPR prefetch, padded LDS rows (no bank conflicts).
// pp_reduce: float4 sum over 32 partial slices.

typedef _Float16 half8 __attribute__((ext_vector_type(8)));
typedef float f32x4 __attribute__((ext_vector_type(4)));

#define OSTRIDE 12544               // 256*49
#define PSLICE  (512 * 256)
#define WE_U4   (256 * 256 * 8)     // we_t uint4 count (8.4 MB)
#define AT_U4   (256 * 512 * 8)     // A_t  uint4 count (16.8 MB)

// ---- prep ----
// blocks 0..255   (blk=i): we_t[i][o][64 f16] = w[o][i][3s+j] packed per seg
// blocks 256..767 (z=blk-256: i=z>>1, half=z&1): A_t[i][b][64 f16] sparse rows
__global__ __launch_bounds__(256)
void pp_prep(const float* __restrict__ x, const float* __restrict__ w,
             uint4* __restrict__ we_t, uint4* __restrict__ A_t) {
    __shared__ uint4 sm[256 * 9];        // 36 KB bounce, row stride 9 (pad)
    const int t = threadIdx.x;
    const int blk = blockIdx.x;

    if (blk < 256) {
        const int i = blk;
        const float* src = w + (size_t)t * OSTRIDE + i * 49;   // t = o
        float v[49];
        #pragma unroll
        for (int k = 0; k < 49; ++k) v[k] = src[k];
        #pragma unroll
        for (int q = 0; q < 8; ++q) {    // q covers segs 2q, 2q+1
            auto p0 = __builtin_amdgcn_cvt_pkrtz(v[6*q],   v[6*q+1]);
            auto p1 = __builtin_amdgcn_cvt_pkrtz(v[6*q+2], v[6*q+3]);
            auto p2 = __builtin_amdgcn_cvt_pkrtz(v[6*q+3], v[6*q+4]);
            auto p3 = __builtin_amdgcn_cvt_pkrtz(v[6*q+5], v[6*q+6]);
            uint4 u;
            u.x = __builtin_bit_cast(unsigned int, p0);
            u.y = __builtin_bit_cast(unsigned int, p1);
            u.z = __builtin_bit_cast(unsigned int, p2);
            u.w = __builtin_bit_cast(unsigned int, p3);
            sm[t * 9 + q] = u;
        }
        __syncthreads();
        #pragma unroll
        for (int k = 0; k < 8; ++k) {
            const int u = k * 256 + t;
            we_t[(size_t)i * 2048 + u] = sm[(u >> 3) * 9 + (u & 7)];
        }
    } else {
        const int z = blk - 256;
        const int i = z >> 1;
        const int b = (z & 1) * 256 + t;
        const float xx = x[(size_t)b * 256 + i];
        int id = (int)((xx + 1.0f) * 8.0f);
        id = id < 0 ? 0 : (id > 15 ? 15 : id);
        const float u = (xx - ((float)id * 0.125f - 1.0f)) * 16.0f - 1.0f;
        const float a = u + 1.0f, b2 = u + 0.5f, cc = u - 0.5f, d = u - 1.0f;
        const float c0 = b2 * cc * d  * (-2.0f / 3.0f);
        const float c1 = a  * cc * d  * ( 4.0f / 3.0f);
        const float c2 = a  * b2 * d  * (-4.0f / 3.0f);
        const float c3 = a  * b2 * cc * ( 2.0f / 3.0f);
        auto pA = __builtin_amdgcn_cvt_pkrtz(c0, c1);
        auto pB = __builtin_amdgcn_cvt_pkrtz(c2, c3);
        const uint4 z4 = make_uint4(0u, 0u, 0u, 0u);
        #pragma unroll
        for (int q = 0; q < 8; ++q) sm[t * 9 + q] = z4;   // own region, no sync
        unsigned int* smu = (unsigned int*)sm;
        smu[t * 36 + 2 * id]     = __builtin_bit_cast(unsigned int, pA);
        smu[t * 36 + 2 * id + 1] = __builtin_bit_cast(unsigned int, pB);
        __syncthreads();
        uint4* dst = A_t + ((size_t)i * 512 + (z & 1) * 256) * 8;
        #pragma unroll
        for (int k = 0; k < 8; ++k) {
            const int uu = k * 256 + t;
            dst[uu] = sm[(uu >> 3) * 9 + (uu & 7)];
        }
    }
}

// ---- gemm: grid (32 ks, 4 mt, 2 nt) x 256 thr ----
__global__ __launch_bounds__(256)
void pp_gemm(const uint4* __restrict__ A_t, const uint4* __restrict__ we_t,
             float* __restrict__ part) {
    __shared__ unsigned int smA[128 * 36];   // 128 rows x (32 dw + 4 pad) = 18 KB
    __shared__ unsigned int smB[128 * 36];

    const int t = threadIdx.x;
    const int wave = t >> 6, lane = t & 63;
    const int quad = lane >> 4, l16 = lane & 15;
    const int ks = blockIdx.x;               // K-chunk: i = ks*8 .. +7
    const int b0 = blockIdx.y * 128;
    const int o0 = blockIdx.z * 128;
    const int i_base = ks * 8;
    const int wm = wave >> 1, wn = wave & 1; // 2x2 wave grid, 64x64 each
    const int r = t >> 1, h = t & 1;         // staging: row 0..127, half

    f32x4 acc[4][4];
    #pragma unroll
    for (int a = 0; a < 4; ++a)
        #pragma unroll
        for (int b = 0; b < 4; ++b) acc[a][b] = (f32x4){0.f, 0.f, 0.f, 0.f};

    uint4 pa[4], pb[4];
    {   // preload it=0
        const uint4* ga = A_t + ((size_t)i_base * 512 + b0 + r) * 8 + h * 4;
        const uint4* gb = we_t + ((size_t)i_base * 256 + o0 + r) * 8 + h * 4;
        #pragma unroll
        for (int q = 0; q < 4; ++q) { pa[q] = ga[q]; pb[q] = gb[q]; }
    }

    #pragma unroll
    for (int it = 0; it < 8; ++it) {
        if (it) __syncthreads();             // prior compute done with LDS
        #pragma unroll
        for (int q = 0; q < 4; ++q) {
            *(uint4*)&smA[r * 36 + h * 16 + q * 4] = pa[q];
            *(uint4*)&smB[r * 36 + h * 16 + q * 4] = pb[q];
        }
        __syncthreads();                     // tile visible
        if (it < 7) {                        // prefetch next (hides under MFMA)
            const int i = i_base + it + 1;
            const uint4* ga = A_t + ((size_t)i * 512 + b0 + r) * 8 + h * 4;
            const uint4* gb = we_t + ((size_t)i * 256 + o0 + r) * 8 + h * 4;
            #pragma unroll
            for (int q = 0; q < 4; ++q) { pa[q] = ga[q]; pb[q] = gb[q]; }
        }
        #pragma unroll
        for (int k2 = 0; k2 < 2; ++k2) {     // two 32-wide k-steps
            half8 av[4], bv[4];
            #pragma unroll
            for (int mi = 0; mi < 4; ++mi)
                av[mi] = __builtin_bit_cast(half8, *(const uint4*)
                    &smA[(wm * 64 + mi * 16 + l16) * 36 + k2 * 16 + quad * 4]);
            #pragma unroll
            for (int ni = 0; ni < 4; ++ni)
                bv[ni] = __builtin_bit_cast(half8, *(const uint4*)
                    &smB[(wn * 64 + ni * 16 + l16) * 36 + k2 * 16 + quad * 4]);
            #pragma unroll
            for (int mi = 0; mi < 4; ++mi)
                #pragma unroll
                for (int ni = 0; ni < 4; ++ni)
                    acc[mi][ni] = __builtin_amdgcn_mfma_f32_16x16x32_f16(
                        av[mi], bv[ni], acc[mi][ni], 0, 0, 0);
        }
    }

    // epilogue: C/D col = l16, row = quad*4 + reg (m89-verified, dtype-indep)
    float* dst = part + (size_t)ks * PSLICE;
    #pragma unroll
    for (int mi = 0; mi < 4; ++mi)
        #pragma unroll
        for (int ni = 0; ni < 4; ++ni) {
            const int bb = b0 + wm * 64 + mi * 16 + quad * 4;
            const int oo = o0 + wn * 64 + ni * 16 + l16;
            #pragma unroll
            for (int rr = 0; rr < 4; ++rr)
                dst[(size_t)(bb + rr) * 256 + oo] = acc[mi][ni][rr];
        }
}

__global__ __launch_bounds__(256)
void pp_reduce(const float* __restrict__ part, float* __restrict__ out) {
    const size_t off4 = (size_t)blockIdx.x * 256 + threadIdx.x;
    const float4* p4 = (const float4*)part;
    float4 s = make_float4(0.f, 0.f, 0.f, 0.f);
    #pragma unroll
    for (int k = 0; k < 32; ++k) {
        float4 v = p4[(size_t)k * (PSLICE / 4) + off4];
        s.x += v.x; s.y += v.y; s.z += v.z; s.w += v.w;
    }
    ((float4*)out)[off4] = s;
}

extern "C" void kernel_launch(void* const* d_in, const int* in_sizes, int n_in,
                              void* d_out, int out_size, void* d_ws, size_t ws_size,
                              hipStream_t stream) {
    const float* x = (const float*)d_in[0];
    const float* w = (const float*)d_in[1];
    float* out = (float*)d_out;
    uint4* we_t = (uint4*)d_ws;                                   // 8.4 MB
    uint4* A_t  = we_t + WE_U4;                                   // 16.8 MB
    float* part = (float*)(A_t + AT_U4);                          // 16.8 MB
    (void)ws_size; (void)n_in; (void)in_sizes; (void)out_size;

    pp_prep<<<dim3(768), 256, 0, stream>>>(x, w, we_t, A_t);
    pp_gemm<<<dim3(32, 4, 2), 256, 0, stream>>>(A_t, we_t, part);
    pp_reduce<<<dim3(128), 256, 0, stream>>>(part, out);
}